// Round 1
// baseline (359.853 us; speedup 1.0000x reference)
//
#include <hip/hip_runtime.h>
#include <cstddef>

#define LL 4096
#define BB 2
#define DD 256
#define NEL ((size_t)BB * LL * DD) /* 2097152 */

__device__ __forceinline__ float4 ld4(const float* p) { return *reinterpret_cast<const float4*>(p); }
__device__ __forceinline__ void st4(float* p, const float4 v) { *reinterpret_cast<float4*>(p) = v; }

#define UNPK(arr, base, v) do { arr[(base)] = v.x; arr[(base)+1] = v.y; arr[(base)+2] = v.z; arr[(base)+3] = v.w; } while (0)

// ---------------- weight transpose prep ----------------
// ws weight region layout (floats):
//  inWt   @ 0      : (256 k, 512 o)   from in_proj_W   (512,256)
//  extWt  @ 131072 : (256,256)        from extra_proj_W(256,256)
//  cwWt   @ 196608 : (512 k, 256 o)   from cw_W        (256,512)
//  outWt  @ 327680 : (256,256)        from out_proj_W  (256,256)
//  xpfWt  @ 393216 : (256 k, 48 o)    from xprojf_W    (48,256)
//  xpbWt  @ 405504 : (256 k, 48 o)    from xprojb_W    (48,256)
__global__ __launch_bounds__(256) void prep_transpose(
    const float* __restrict__ inW, const float* __restrict__ extW,
    const float* __restrict__ cwW, const float* __restrict__ outW,
    const float* __restrict__ xpf, const float* __restrict__ xpb,
    float* __restrict__ wsW)
{
    int idx = blockIdx.x * 256 + threadIdx.x;
    if (idx < 131072) {
        int r = idx >> 8, c = idx & 255;
        wsW[c * 512 + r] = inW[idx];
    } else if (idx < 196608) {
        int i = idx - 131072; int r = i >> 8, c = i & 255;
        wsW[131072 + c * 256 + r] = extW[i];
    } else if (idx < 327680) {
        int i = idx - 196608; int r = i >> 9, c = i & 511;
        wsW[196608 + c * 256 + r] = cwW[i];
    } else if (idx < 393216) {
        int i = idx - 327680; int r = i >> 8, c = i & 255;
        wsW[327680 + c * 256 + r] = outW[i];
    } else if (idx < 405504) {
        int i = idx - 393216; int r = i >> 8, c = i & 255;
        wsW[393216 + c * 48 + r] = xpf[i];
    } else if (idx < 417792) {
        int i = idx - 405504; int r = i >> 8, c = i & 255;
        wsW[405504 + c * 48 + r] = xpb[i];
    }
}

// ---------------- row LayerNorm (256 cols), one wave per row ----------------
__global__ __launch_bounds__(64) void ln_rows(
    const float* __restrict__ in, float* __restrict__ out,
    const float* __restrict__ g, const float* __restrict__ bb)
{
    const int row = blockIdx.x;
    const int t = threadIdx.x;
    const size_t off = (size_t)row * 256 + t * 4;
    float4 v = ld4(&in[off]);
    float s = v.x + v.y + v.z + v.w;
    float s2 = v.x * v.x + v.y * v.y + v.z * v.z + v.w * v.w;
#pragma unroll
    for (int dl = 1; dl < 64; dl <<= 1) { s += __shfl_xor(s, dl); s2 += __shfl_xor(s2, dl); }
    const float m = s * (1.f / 256.f);
    const float var = s2 * (1.f / 256.f) - m * m;
    const float rstd = rsqrtf(var + 1e-5f);
    const float4 gv = ld4(&g[t * 4]);
    const float4 bv = ld4(&bb[t * 4]);
    float4 r;
    r.x = (v.x - m) * rstd * gv.x + bv.x;
    r.y = (v.y - m) * rstd * gv.y + bv.y;
    r.z = (v.z - m) * rstd * gv.z + bv.z;
    r.w = (v.w - m) * rstd * gv.w + bv.w;
    st4(&out[off], r);
}

// ---------------- generic tiled SGEMM with fused epilogues ----------------
// mode 0: fused projections. A0=x0n, A1=x1n. grid (128,16).
//   n0<256   -> x part   (transposed write to out0 = xT)
//   n0<512   -> z part   (transposed write to out1 = zT)
//   n0<768   -> ep part  (direct write to out2, A=x1n)
//   n0<1024  -> w part   (K=512 concat, sigmoid(+cw_b), out3)
// mode 1: xdbl. A0=ep, N=48 masked, grid (128,1,2) z=dir, out0/out1 = xdbl_f/b.
// mode 2: out-proj. A0=ynorm, grid (128,4), out0 = o.
__global__ __launch_bounds__(256) void gemm_all(
    const int mode,
    const float* __restrict__ A0, const float* __restrict__ A1,
    const float* __restrict__ wsW, const float* __restrict__ cwb,
    float* __restrict__ out0, float* __restrict__ out1,
    float* __restrict__ out2, float* __restrict__ out3)
{
    __shared__ float As[16][64];
    __shared__ float Ws[16][64];
    __shared__ float Ct[64][65];
    const int t = threadIdx.x;
    const int m0 = blockIdx.x * 64;
    const int n0 = blockIdx.y * 64;
    const float* Wt; int ldw, wcol, K;
    int seg = 0;
    if (mode == 0) {
        seg = (n0 < 512) ? 0 : (n0 < 768 ? 1 : 2);
        if (seg == 0)      { Wt = wsW;          ldw = 512; wcol = n0;       K = 256; }
        else if (seg == 1) { Wt = wsW + 131072; ldw = 256; wcol = n0 - 512; K = 256; }
        else               { Wt = wsW + 196608; ldw = 256; wcol = n0 - 768; K = 512; }
    } else if (mode == 1) {
        Wt = wsW + (blockIdx.z ? 405504 : 393216); ldw = 48; wcol = 0; K = 256;
    } else {
        Wt = wsW + 327680; ldw = 256; wcol = n0; K = 256;
    }
    const int ar = t >> 2, ak = (t & 3) * 4;
    const int wk = t >> 4, wn = (t & 15) * 4;
    const int tm = (t >> 4) * 4, tn = (t & 15) * 4;
    float acc[4][4] = {{0.f, 0.f, 0.f, 0.f}, {0.f, 0.f, 0.f, 0.f}, {0.f, 0.f, 0.f, 0.f}, {0.f, 0.f, 0.f, 0.f}};
    for (int k0 = 0; k0 < K; k0 += 16) {
        const float* Asrc = A0;
        int kk = k0 + ak;
        if (mode == 0) {
            if (seg == 1) Asrc = A1;
            else if (seg == 2 && k0 >= 256) { Asrc = A1; kk -= 256; }
        }
        const float4 av = ld4(&Asrc[(size_t)(m0 + ar) * 256 + kk]);
        float4 wv;
        if (mode == 1 && wn >= 48) wv = make_float4(0.f, 0.f, 0.f, 0.f);
        else wv = ld4(&Wt[(size_t)(k0 + wk) * ldw + wcol + wn]);
        __syncthreads();
        As[ak + 0][ar] = av.x; As[ak + 1][ar] = av.y; As[ak + 2][ar] = av.z; As[ak + 3][ar] = av.w;
        st4(&Ws[wk][wn], wv);
        __syncthreads();
#pragma unroll
        for (int q = 0; q < 16; ++q) {
            const float4 a4 = ld4(&As[q][tm]);
            const float4 b4 = ld4(&Ws[q][tn]);
            acc[0][0] = fmaf(a4.x, b4.x, acc[0][0]); acc[0][1] = fmaf(a4.x, b4.y, acc[0][1]);
            acc[0][2] = fmaf(a4.x, b4.z, acc[0][2]); acc[0][3] = fmaf(a4.x, b4.w, acc[0][3]);
            acc[1][0] = fmaf(a4.y, b4.x, acc[1][0]); acc[1][1] = fmaf(a4.y, b4.y, acc[1][1]);
            acc[1][2] = fmaf(a4.y, b4.z, acc[1][2]); acc[1][3] = fmaf(a4.y, b4.w, acc[1][3]);
            acc[2][0] = fmaf(a4.z, b4.x, acc[2][0]); acc[2][1] = fmaf(a4.z, b4.y, acc[2][1]);
            acc[2][2] = fmaf(a4.z, b4.z, acc[2][2]); acc[2][3] = fmaf(a4.z, b4.w, acc[2][3]);
            acc[3][0] = fmaf(a4.w, b4.x, acc[3][0]); acc[3][1] = fmaf(a4.w, b4.y, acc[3][1]);
            acc[3][2] = fmaf(a4.w, b4.z, acc[3][2]); acc[3][3] = fmaf(a4.w, b4.w, acc[3][3]);
        }
    }
    if (mode == 0 && seg == 0) {
#pragma unroll
        for (int i = 0; i < 4; ++i)
            st4(&Ct[tm + i][tn], make_float4(acc[i][0], acc[i][1], acc[i][2], acc[i][3]));
        __syncthreads();
        const int b = m0 >> 12;
        const int l0 = m0 & (LL - 1);
        float* dst = (n0 < 256) ? out0 : out1;
        const int dbase = (n0 < 256) ? n0 : n0 - 256;
        const int lrow = t & 63;
        const int ig = t >> 6;
#pragma unroll
        for (int it = 0; it < 16; ++it) {
            const int dcol = it * 4 + ig;
            dst[((size_t)b * DD + dbase + dcol) * LL + l0 + lrow] = Ct[lrow][dcol];
        }
    } else if (mode == 0 && seg == 2) {
        const int col = n0 - 768 + tn;
        const float4 bv = ld4(&cwb[col]);
#pragma unroll
        for (int i = 0; i < 4; ++i) {
            float4 r;
            r.x = 1.f / (1.f + expf(-(acc[i][0] + bv.x)));
            r.y = 1.f / (1.f + expf(-(acc[i][1] + bv.y)));
            r.z = 1.f / (1.f + expf(-(acc[i][2] + bv.z)));
            r.w = 1.f / (1.f + expf(-(acc[i][3] + bv.w)));
            st4(&out3[(size_t)(m0 + tm + i) * 256 + col], r);
        }
    } else if (mode == 1) {
        if (tn < 48) {
            float* dst = blockIdx.z ? out1 : out0;
#pragma unroll
            for (int i = 0; i < 4; ++i)
                st4(&dst[(size_t)(m0 + tm + i) * 48 + tn], make_float4(acc[i][0], acc[i][1], acc[i][2], acc[i][3]));
        }
    } else {
        float* dst; int col;
        if (mode == 0) { dst = out2; col = n0 - 512 + tn; }
        else { dst = out0; col = n0 + tn; }
#pragma unroll
        for (int i = 0; i < 4; ++i)
            st4(&dst[(size_t)(m0 + tm + i) * 256 + col], make_float4(acc[i][0], acc[i][1], acc[i][2], acc[i][3]));
    }
}

// ---------------- selective scan (conv + dt + SSM + gate fused) ----------------
// grid (256 d, 2 b, 2 dir), block 256. Thread j owns scan positions p=[16j,16j+16).
__global__ __launch_bounds__(256) void scan_kernel(
    const float* __restrict__ xT, const float* __restrict__ zT,
    const float* __restrict__ xdblF, const float* __restrict__ xdblB,
    const float* __restrict__ cfW, const float* __restrict__ cfB,
    const float* __restrict__ dtfW, const float* __restrict__ dtfBs,
    const float* __restrict__ AlF, const float* __restrict__ DF,
    const float* __restrict__ cbW, const float* __restrict__ cbB,
    const float* __restrict__ dtbW, const float* __restrict__ dtbBs,
    const float* __restrict__ AlB, const float* __restrict__ DB,
    float* __restrict__ yF, float* __restrict__ yB)
{
    const int d = blockIdx.x;
    const int b = blockIdx.y;
    const int dir = blockIdx.z;
    const int t = threadIdx.x;
    const float* xdbl = dir ? xdblB : xdblF;
    const float* cW  = dir ? cbW  : cfW;
    const float* cBv = dir ? cbB  : cfB;
    const float* dW  = dir ? dtbW : dtfW;
    const float* dBs = dir ? dtbBs : dtfBs;
    const float* Al  = dir ? AlB  : AlF;
    const float* Dp  = dir ? DB   : DF;
    float* yout = dir ? yB : yF;

    float A2[16], dtw[16];
#pragma unroll
    for (int n = 0; n < 16; ++n) A2[n] = -expf(Al[d * 16 + n]) * 1.4426950408889634f;
#pragma unroll
    for (int r = 0; r < 16; ++r) dtw[r] = dW[d * 16 + r];
    const float dtbias = dBs[d];
    const float Dd = Dp[d];
    const float c0 = cW[d * 4 + 0], c1 = cW[d * 4 + 1], c2 = cW[d * 4 + 2], c3 = cW[d * 4 + 3];
    const float cbias = cBv[d];

    const int p0 = t * 16;
    const size_t xbase = ((size_t)b * DD + d) * LL;
    const int ls = LL - 16 - p0;

    // x window xq[i] = xseq(p0 - 3 + i), i=0..18 (xseq(p) = x at l = dir ? LL-1-p : p)
    float xq[19];
    if (dir == 0) {
#pragma unroll
        for (int k = 0; k < 4; ++k) {
            float4 v = ld4(&xT[xbase + p0 + 4 * k]);
            xq[3 + 4 * k] = v.x; xq[4 + 4 * k] = v.y; xq[5 + 4 * k] = v.z; xq[6 + 4 * k] = v.w;
        }
        xq[2] = (p0 >= 1) ? xT[xbase + p0 - 1] : 0.f;
        xq[1] = (p0 >= 2) ? xT[xbase + p0 - 2] : 0.f;
        xq[0] = (p0 >= 3) ? xT[xbase + p0 - 3] : 0.f;
    } else {
#pragma unroll
        for (int k = 0; k < 4; ++k) {
            float4 v = ld4(&xT[xbase + ls + 4 * k]);
            xq[18 - 4 * k] = v.x; xq[17 - 4 * k] = v.y; xq[16 - 4 * k] = v.z; xq[15 - 4 * k] = v.w;
        }
        xq[2] = (p0 >= 1) ? xT[xbase + LL - p0] : 0.f;
        xq[1] = (p0 >= 2) ? xT[xbase + LL + 1 - p0] : 0.f;
        xq[0] = (p0 >= 3) ? xT[xbase + LL + 2 - p0] : 0.f;
    }

    float xs[16];
#pragma unroll
    for (int s = 0; s < 16; ++s) {
        float c = fmaf(xq[s], c0, fmaf(xq[s + 1], c1, fmaf(xq[s + 2], c2, fmaf(xq[s + 3], c3, cbias))));
        xs[s] = c / (1.f + expf(-c));
    }

    // phase A: chunk-local scan (P = prod dA, S = local h with h_in = 0)
    float P[16], S[16], dtv[16];
#pragma unroll
    for (int n = 0; n < 16; ++n) { P[n] = 1.f; S[n] = 0.f; }
#pragma unroll
    for (int s = 0; s < 16; ++s) {
        const int l = dir ? (LL - 1 - (p0 + s)) : (p0 + s);
        const float* row = xdbl + ((size_t)b * LL + l) * 48;
        float4 r0 = ld4(row), r1 = ld4(row + 4), r2 = ld4(row + 8), r3 = ld4(row + 12);
        float dot = r0.x * dtw[0] + r0.y * dtw[1] + r0.z * dtw[2] + r0.w * dtw[3]
                  + r1.x * dtw[4] + r1.y * dtw[5] + r1.z * dtw[6] + r1.w * dtw[7]
                  + r2.x * dtw[8] + r2.y * dtw[9] + r2.z * dtw[10] + r2.w * dtw[11]
                  + r3.x * dtw[12] + r3.y * dtw[13] + r3.z * dtw[14] + r3.w * dtw[15];
        dot += dtbias;
        const float dtval = fmaxf(dot, 0.f) + log1pf(expf(-fabsf(dot)));
        dtv[s] = dtval;
        const float dtxs = dtval * xs[s];
        float Bv[16];
        {
            float4 b0 = ld4(row + 16), b1 = ld4(row + 20), b2 = ld4(row + 24), b3 = ld4(row + 28);
            UNPK(Bv, 0, b0); UNPK(Bv, 4, b1); UNPK(Bv, 8, b2); UNPK(Bv, 12, b3);
        }
#pragma unroll
        for (int n = 0; n < 16; ++n) {
            const float dA = exp2f(dtval * A2[n]);
            S[n] = fmaf(dA, S[n], dtxs * Bv[n]);
            P[n] *= dA;
        }
    }

    // block-wide inclusive scan over chunks (combine: (a1,b1)∘(a2,b2) = (a1a2, a2b1+b2))
    const int lane = t & 63;
    const int wvid = t >> 6;
#pragma unroll
    for (int dl = 1; dl < 64; dl <<= 1) {
#pragma unroll
        for (int n = 0; n < 16; ++n) {
            const float Pp = __shfl_up(P[n], dl);
            const float Sp = __shfl_up(S[n], dl);
            if (lane >= dl) {
                S[n] = fmaf(P[n], Sp, S[n]);
                P[n] *= Pp;
            }
        }
    }
    __shared__ float wPs[4][16];
    __shared__ float wSs[4][16];
    if (lane == 63) {
#pragma unroll
        for (int n = 0; n < 16; ++n) { wPs[wvid][n] = P[n]; wSs[wvid][n] = S[n]; }
    }
    __syncthreads();
    float WS[16];
#pragma unroll
    for (int n = 0; n < 16; ++n) WS[n] = 0.f;
    for (int w = 0; w < wvid; ++w) {
#pragma unroll
        for (int n = 0; n < 16; ++n) WS[n] = fmaf(wPs[w][n], WS[n], wSs[w][n]);
    }
    float h[16];
#pragma unroll
    for (int n = 0; n < 16; ++n) {
        float Pex = __shfl_up(P[n], 1);
        float Sex = __shfl_up(S[n], 1);
        if (lane == 0) { Pex = 1.f; Sex = 0.f; }
        h[n] = fmaf(Pex, WS[n], Sex);
    }

    // z gate window
    float zq[16];
    if (dir == 0) {
#pragma unroll
        for (int k = 0; k < 4; ++k) {
            float4 v = ld4(&zT[xbase + p0 + 4 * k]);
            zq[4 * k] = v.x; zq[4 * k + 1] = v.y; zq[4 * k + 2] = v.z; zq[4 * k + 3] = v.w;
        }
    } else {
#pragma unroll
        for (int k = 0; k < 4; ++k) {
            float4 v = ld4(&zT[xbase + ls + 4 * k]);
            zq[15 - 4 * k] = v.x; zq[14 - 4 * k] = v.y; zq[13 - 4 * k] = v.z; zq[12 - 4 * k] = v.w;
        }
    }

    // phase C: replay with correct h_in, emit y
    float yv[16];
#pragma unroll
    for (int s = 0; s < 16; ++s) {
        const int l = dir ? (LL - 1 - (p0 + s)) : (p0 + s);
        const float* row = xdbl + ((size_t)b * LL + l) * 48;
        float Bv[16], Cv[16];
        {
            float4 b0 = ld4(row + 16), b1 = ld4(row + 20), b2 = ld4(row + 24), b3 = ld4(row + 28);
            UNPK(Bv, 0, b0); UNPK(Bv, 4, b1); UNPK(Bv, 8, b2); UNPK(Bv, 12, b3);
            float4 q0 = ld4(row + 32), q1 = ld4(row + 36), q2 = ld4(row + 40), q3 = ld4(row + 44);
            UNPK(Cv, 0, q0); UNPK(Cv, 4, q1); UNPK(Cv, 8, q2); UNPK(Cv, 12, q3);
        }
        const float dtval = dtv[s];
        const float dtxs = dtval * xs[s];
        float y = 0.f;
#pragma unroll
        for (int n = 0; n < 16; ++n) {
            const float dA = exp2f(dtval * A2[n]);
            h[n] = fmaf(dA, h[n], dtxs * Bv[n]);
            y = fmaf(h[n], Cv[n], y);
        }
        y = fmaf(Dd, xs[s], y);
        const float zz = zq[s];
        y *= zz / (1.f + expf(-zz));
        yv[s] = y;
    }

    if (dir == 0) {
#pragma unroll
        for (int k = 0; k < 4; ++k)
            st4(&yout[xbase + p0 + 4 * k], make_float4(yv[4 * k], yv[4 * k + 1], yv[4 * k + 2], yv[4 * k + 3]));
    } else {
#pragma unroll
        for (int k = 0; k < 4; ++k)
            st4(&yout[xbase + ls + 4 * k], make_float4(yv[15 - 4 * k], yv[14 - 4 * k], yv[13 - 4 * k], yv[12 - 4 * k]));
    }
}

// ---------------- transpose (B,256,L)->(B,L,256) with (yf+yb)*0.5 ----------------
__global__ __launch_bounds__(256) void transpose_combine(
    const float* __restrict__ yF, const float* __restrict__ yB, float* __restrict__ ysum)
{
    __shared__ float tile[64][65];
    const int b = blockIdx.z;
    const int l0 = blockIdx.x * 64;
    const int d0 = blockIdx.y * 64;
    const int t = threadIdx.x;
    const int j = t & 63;
    const int i0 = t >> 6;
#pragma unroll
    for (int ii = 0; ii < 16; ++ii) {
        const int i = ii * 4 + i0;
        const size_t off = ((size_t)b * DD + d0 + i) * LL + l0 + j;
        tile[i][j] = (yF[off] + yB[off]) * 0.5f;
    }
    __syncthreads();
#pragma unroll
    for (int jj = 0; jj < 16; ++jj) {
        const int lr = jj * 4 + i0;
        ysum[((size_t)b * LL + l0 + lr) * 256 + d0 + j] = tile[j][lr];
    }
}

// ---------------- post-LN + gated blend + skip ----------------
__global__ __launch_bounds__(64) void final_kernel(
    const float* __restrict__ o, const float* __restrict__ w,
    const float* __restrict__ x0n, const float* __restrict__ in0,
    const float* __restrict__ pg, const float* __restrict__ pb,
    float* __restrict__ outp)
{
    const int row = blockIdx.x;
    const int t = threadIdx.x;
    const size_t off = (size_t)row * 256 + t * 4;
    float4 v = ld4(&o[off]);
    float s = v.x + v.y + v.z + v.w;
    float s2 = v.x * v.x + v.y * v.y + v.z * v.z + v.w * v.w;
#pragma unroll
    for (int dl = 1; dl < 64; dl <<= 1) { s += __shfl_xor(s, dl); s2 += __shfl_xor(s2, dl); }
    const float m = s * (1.f / 256.f);
    const float var = s2 * (1.f / 256.f) - m * m;
    const float rstd = rsqrtf(var + 1e-5f);
    const float4 gv = ld4(&pg[t * 4]);
    const float4 bv = ld4(&pb[t * 4]);
    const float4 wv = ld4(&w[off]);
    const float4 xv = ld4(&x0n[off]);
    const float4 iv = ld4(&in0[off]);
    float4 r;
    r.x = ((v.x - m) * rstd * gv.x + bv.x) * wv.x + xv.x * (1.f - wv.x) + iv.x;
    r.y = ((v.y - m) * rstd * gv.y + bv.y) * wv.y + xv.y * (1.f - wv.y) + iv.y;
    r.z = ((v.z - m) * rstd * gv.z + bv.z) * wv.z + xv.z * (1.f - wv.z) + iv.z;
    r.w = ((v.w - m) * rstd * gv.w + bv.w) * wv.w + xv.w * (1.f - wv.w) + iv.w;
    st4(&outp[off], r);
}

extern "C" void kernel_launch(void* const* d_in, const int* in_sizes, int n_in,
                              void* d_out, int out_size, void* d_ws, size_t ws_size,
                              hipStream_t stream) {
    (void)in_sizes; (void)n_in; (void)out_size; (void)ws_size;
    const float* in0      = (const float*)d_in[0];
    const float* in1      = (const float*)d_in[1];
    const float* norm0_g  = (const float*)d_in[2];
    const float* norm0_b  = (const float*)d_in[3];
    const float* norm1_g  = (const float*)d_in[4];
    const float* norm1_b  = (const float*)d_in[5];
    const float* cw_W     = (const float*)d_in[6];
    const float* cw_b     = (const float*)d_in[7];
    const float* in_proj_W    = (const float*)d_in[8];
    const float* extra_proj_W = (const float*)d_in[9];
    const float* convf_W  = (const float*)d_in[10];
    const float* convf_b  = (const float*)d_in[11];
    const float* xprojf_W = (const float*)d_in[12];
    const float* dtf_W    = (const float*)d_in[13];
    const float* dtf_b    = (const float*)d_in[14];
    const float* A_log_f  = (const float*)d_in[15];
    const float* D_f      = (const float*)d_in[16];
    const float* convb_W  = (const float*)d_in[17];
    const float* convb_b  = (const float*)d_in[18];
    const float* xprojb_W = (const float*)d_in[19];
    const float* dtb_W    = (const float*)d_in[20];
    const float* dtb_b    = (const float*)d_in[21];
    const float* A_log_b  = (const float*)d_in[22];
    const float* D_b      = (const float*)d_in[23];
    const float* outnorm_g = (const float*)d_in[24];
    const float* outnorm_b = (const float*)d_in[25];
    const float* out_proj_W = (const float*)d_in[26];
    const float* post_g   = (const float*)d_in[27];
    const float* post_b   = (const float*)d_in[28];

    float* ws = (float*)d_ws;
    float* x0n   = ws;
    float* x1n   = ws + NEL;
    float* xT    = ws + 2 * NEL;
    float* zT    = ws + 3 * NEL;
    float* ep    = ws + 4 * NEL;
    float* wbuf  = ws + 5 * NEL;
    float* yFb   = ws + 6 * NEL;
    float* yBb   = ws + 7 * NEL;
    float* xdblF = ws + 8 * NEL;
    float* xdblB = xdblF + (size_t)BB * LL * 48;
    float* wsW   = xdblB + (size_t)BB * LL * 48;
    float* ysum  = xT;   // reuse (xT dead after scan)
    float* ynorm = zT;   // reuse (zT dead after scan)
    float* obuf  = ep;   // reuse (ep dead after xdbl gemm)

    prep_transpose<<<1632, 256, 0, stream>>>(in_proj_W, extra_proj_W, cw_W, out_proj_W,
                                             xprojf_W, xprojb_W, wsW);
    ln_rows<<<BB * LL, 64, 0, stream>>>(in0, x0n, norm0_g, norm0_b);
    ln_rows<<<BB * LL, 64, 0, stream>>>(in1, x1n, norm1_g, norm1_b);
    gemm_all<<<dim3(128, 16, 1), 256, 0, stream>>>(0, x0n, x1n, wsW, cw_b, xT, zT, ep, wbuf);
    gemm_all<<<dim3(128, 1, 2), 256, 0, stream>>>(1, ep, nullptr, wsW, cw_b, xdblF, xdblB, nullptr, nullptr);
    scan_kernel<<<dim3(256, 2, 2), 256, 0, stream>>>(xT, zT, xdblF, xdblB,
                                                     convf_W, convf_b, dtf_W, dtf_b, A_log_f, D_f,
                                                     convb_W, convb_b, dtb_W, dtb_b, A_log_b, D_b,
                                                     yFb, yBb);
    transpose_combine<<<dim3(64, 4, 2), 256, 0, stream>>>(yFb, yBb, ysum);
    ln_rows<<<BB * LL, 64, 0, stream>>>(ysum, ynorm, outnorm_g, outnorm_b);
    gemm_all<<<dim3(128, 4, 1), 256, 0, stream>>>(2, ynorm, nullptr, wsW, cw_b, obuf, nullptr, nullptr, nullptr);
    final_kernel<<<BB * LL, 64, 0, stream>>>(obuf, wbuf, x0n, in0, post_g, post_b, (float*)d_out);
}